// Round 8
// baseline (957.898 us; speedup 1.0000x reference)
//
#include <hip/hip_runtime.h>
#include <math.h>

#define NNODES 65536
#define CH 12
#define NHEADS 8
#define NEDGE 1048576
#define NITEMS (NEDGE + NNODES)
#define NBATCH 64
#define TSTEPS 12

// ---- prep: u[h][k] = sum_c att_src[h][c]*W[(h*12+c)][k], v likewise --------
__global__ __launch_bounds__(128) void gat_prep(
    const float* __restrict__ W, const float* __restrict__ as,
    const float* __restrict__ ad, float* __restrict__ uv) {
  int t = threadIdx.x;
  if (t < 96) {
    int h = t / 12, k = t % 12;
    float su = 0.f, sv = 0.f;
#pragma unroll
    for (int c = 0; c < 12; c++) {
      float w = W[(h * 12 + c) * 12 + k];
      su += as[h * 12 + c] * w;
      sv += ad[h * 12 + c] * w;
    }
    uv[t] = su; uv[96 + t] = sv;
  }
}

// ---- per-node attention scalars: a_src[n][h]=u_h.x_n, a_dst[n][h]=v_h.x_n --
__global__ __launch_bounds__(256) void gat_node2(
    const float* __restrict__ x, const float* __restrict__ uv,
    float* __restrict__ a_src, float* __restrict__ a_dst) {
  __shared__ float su[96], sv[96];
  int tid = threadIdx.x;
  if (tid < 96) { su[tid] = uv[tid]; sv[tid] = uv[96 + tid]; }
  __syncthreads();
  int n = blockIdx.x * 256 + tid;
  const float4* xp = (const float4*)(x + (size_t)n * 12);
  float4 x0 = xp[0], x1 = xp[1], x2 = xp[2];
  float xv[12] = {x0.x,x0.y,x0.z,x0.w,x1.x,x1.y,x1.z,x1.w,x2.x,x2.y,x2.z,x2.w};
  float as[8], ad[8];
#pragma unroll
  for (int h = 0; h < 8; h++) {
    float s1 = 0.f, s2 = 0.f;
#pragma unroll
    for (int k = 0; k < 12; k++) { s1 += su[h*12+k]*xv[k]; s2 += sv[h*12+k]*xv[k]; }
    as[h] = s1; ad[h] = s2;
  }
  float4* ap = (float4*)(a_src + (size_t)n * 8);
  float4* dp = (float4*)(a_dst + (size_t)n * 8);
  ap[0] = make_float4(as[0],as[1],as[2],as[3]);
  ap[1] = make_float4(as[4],as[5],as[6],as[7]);
  dp[0] = make_float4(ad[0],ad[1],ad[2],ad[3]);
  dp[1] = make_float4(ad[4],ad[5],ad[6],ad[7]);
}

// ---- CSR build: count / scan / scatter -------------------------------------
__global__ __launch_bounds__(256) void csr_count(const int* __restrict__ ei,
                                                 int* __restrict__ counts) {
  int e = blockIdx.x * 256 + threadIdx.x;
  if (e >= NITEMS) return;
  int d = (e < NEDGE) ? ei[NEDGE + e] : (e - NEDGE);
  atomicAdd(&counts[d], 1);
}

__global__ __launch_bounds__(1024) void csr_scan(const int* __restrict__ counts,
                                                 int* __restrict__ offsets,
                                                 int* __restrict__ cursor) {
  __shared__ int part[1024];
  int t = threadIdx.x;
  int base = t * 64;
  int s = 0;
  for (int i = 0; i < 64; i++) s += counts[base + i];
  part[t] = s;
  __syncthreads();
  for (int off = 1; off < 1024; off <<= 1) {
    int v = (t >= off) ? part[t - off] : 0;
    __syncthreads();
    part[t] += v;
    __syncthreads();
  }
  int run = (t == 0) ? 0 : part[t - 1];
  for (int i = 0; i < 64; i++) {
    offsets[base + i] = run;
    cursor[base + i] = run;
    run += counts[base + i];
  }
}

__global__ __launch_bounds__(256) void csr_scatter(const int* __restrict__ ei,
                                                   int* __restrict__ cursor,
                                                   int* __restrict__ csr) {
  int e = blockIdx.x * 256 + threadIdx.x;
  if (e >= NITEMS) return;
  int s, d;
  if (e < NEDGE) { s = ei[e]; d = ei[NEDGE + e]; } else { s = d = e - NEDGE; }
  int pos = atomicAdd(&cursor[d], 1);
  csr[pos] = s;
}

// ---- fused GAT aggregation: one WAVE per dst node --------------------------
// lane = h(0..7) + 8*sub(0..7): 8 heads x 8-way edge parallelism.
// denom: sub-reduce (xor 8,16,32). acc: per-lane partial; y = W_h . acc_part
// (linear), then full 64-lane butterfly gives sum over heads and subs.
__global__ __launch_bounds__(256) void gat_agg(
    const int* __restrict__ offsets, const int* __restrict__ counts,
    const int* __restrict__ csr, const float* __restrict__ a_src,
    const float* __restrict__ a_dst, const float* __restrict__ x,
    const float* __restrict__ gat_W, const float* __restrict__ gat_bias,
    float* __restrict__ gT) {
  __shared__ float sW[1152];
  __shared__ float sB[12];
  int tid = threadIdx.x;
  for (int i = tid; i < 1152; i += 256) sW[i] = gat_W[i];
  if (tid < 12) sB[tid] = gat_bias[tid];
  __syncthreads();
  int wave = tid >> 6, lane = tid & 63;
  int d = blockIdx.x * 4 + wave;
  int h = lane & 7, sub = lane >> 3;
  int start = offsets[d], deg = counts[d];
  float adh = a_dst[(size_t)d * 8 + h];
  float denom = 0.f;
  for (int i = sub; i < deg; i += 8) {
    int s = csr[start + i];
    float e = a_src[(size_t)s * 8 + h] + adh;
    e = e > 0.f ? e : 0.2f * e;
    denom += expf(e);
  }
  // reduce over sub (lanes differing in bits 3..5 share h)
  denom += __shfl_xor(denom, 8);
  denom += __shfl_xor(denom, 16);
  denom += __shfl_xor(denom, 32);
  float inv = 1.f / (denom + 1e-16f);
  float acc[12];
#pragma unroll
  for (int c = 0; c < 12; c++) acc[c] = 0.f;
  for (int i = sub; i < deg; i += 8) {
    int s = csr[start + i];
    float e = a_src[(size_t)s * 8 + h] + adh;
    e = e > 0.f ? e : 0.2f * e;
    float al = expf(e) * inv;
    const float4* xp = (const float4*)(x + (size_t)s * 12);
    float4 x0 = xp[0], x1 = xp[1], x2 = xp[2];
    acc[0] += al*x0.x; acc[1] += al*x0.y; acc[2]  += al*x0.z; acc[3]  += al*x0.w;
    acc[4] += al*x1.x; acc[5] += al*x1.y; acc[6]  += al*x1.z; acc[7]  += al*x1.w;
    acc[8] += al*x2.x; acc[9] += al*x2.y; acc[10] += al*x2.z; acc[11] += al*x2.w;
  }
  // y = W_h . acc_partial  (linear in acc, so reduce after)
  float y[12];
#pragma unroll
  for (int c = 0; c < 12; c++) {
    const float* wr = sW + (h * 12 + c) * 12;
    float t = 0.f;
#pragma unroll
    for (int k = 0; k < 12; k++) t += wr[k] * acc[k];
    y[c] = t;
  }
  // full 64-lane butterfly: sum over heads and subs (no duplication factor)
#pragma unroll
  for (int off = 1; off < 64; off <<= 1) {
#pragma unroll
    for (int c = 0; c < 12; c++) y[c] += __shfl_xor(y[c], off);
  }
  if (lane == 0) {
    int b = d >> 10, np = d & 1023;
#pragma unroll
    for (int t = 0; t < 12; t++)
      gT[((size_t)(t * 64 + b)) * 1024 + np] = y[t] * 0.125f + sB[t];
  }
}

// ---------------- generic tiled GEMM: C[M,N] = A[M,K] @ B[N,K]^T (+bias) ----
// grid: (N/64, M/64, splitK). If ATOMIC: atomicAdd into pre-initialized C.
// Register-prefetch pipeline: next global tile issued before computing current.
template <bool ATOMIC>
__global__ __launch_bounds__(256) void gemm_bt(
    const float* __restrict__ A, const float* __restrict__ B,
    const float* __restrict__ bias0, const float* __restrict__ bias1,
    float* __restrict__ C, int M, int N, int K, int kLen) {
  __shared__ float As[16][68];
  __shared__ float Bs[16][68];
  int m0 = blockIdx.y * 64, n0 = blockIdx.x * 64;
  int k0 = blockIdx.z * kLen;
  int tid = threadIdx.x;
  int lr = tid >> 2, lq = tid & 3;
  int tn = tid & 15, tm = tid >> 4;
  float acc[4][4];
#pragma unroll
  for (int i = 0; i < 4; i++)
#pragma unroll
    for (int j = 0; j < 4; j++) acc[i][j] = 0.f;

  const float* Ap = A + (size_t)(m0 + lr) * K + k0 + lq * 4;
  const float* Bp = B + (size_t)(n0 + lr) * K + k0 + lq * 4;
  float4 a4 = *(const float4*)Ap;
  float4 b4 = *(const float4*)Bp;

  for (int kk = 0; kk < kLen; kk += 16) {
    As[lq * 4 + 0][lr] = a4.x; As[lq * 4 + 1][lr] = a4.y;
    As[lq * 4 + 2][lr] = a4.z; As[lq * 4 + 3][lr] = a4.w;
    Bs[lq * 4 + 0][lr] = b4.x; Bs[lq * 4 + 1][lr] = b4.y;
    Bs[lq * 4 + 2][lr] = b4.z; Bs[lq * 4 + 3][lr] = b4.w;
    __syncthreads();
    float4 a4n, b4n;
    if (kk + 16 < kLen) {
      a4n = *(const float4*)(Ap + kk + 16);
      b4n = *(const float4*)(Bp + kk + 16);
    }
#pragma unroll
    for (int k = 0; k < 16; k++) {
      float4 av = *(const float4*)(&As[k][tm * 4]);
      float4 bv = *(const float4*)(&Bs[k][tn * 4]);
      acc[0][0] += av.x * bv.x; acc[0][1] += av.x * bv.y; acc[0][2] += av.x * bv.z; acc[0][3] += av.x * bv.w;
      acc[1][0] += av.y * bv.x; acc[1][1] += av.y * bv.y; acc[1][2] += av.y * bv.z; acc[1][3] += av.y * bv.w;
      acc[2][0] += av.z * bv.x; acc[2][1] += av.z * bv.y; acc[2][2] += av.z * bv.z; acc[2][3] += av.z * bv.w;
      acc[3][0] += av.w * bv.x; acc[3][1] += av.w * bv.y; acc[3][2] += av.w * bv.z; acc[3][3] += av.w * bv.w;
    }
    __syncthreads();
    a4 = a4n; b4 = b4n;
  }
#pragma unroll
  for (int i = 0; i < 4; i++) {
    int m = m0 + tm * 4 + i;
#pragma unroll
    for (int j = 0; j < 4; j++) {
      int n = n0 + tn * 4 + j;
      float v = acc[i][j];
      if (ATOMIC) {
        atomicAdd(&C[(size_t)m * N + n], v);
      } else {
        v += bias0[n];
        if (bias1) v += bias1[n];
        C[(size_t)m * N + n] = v;
      }
    }
  }
}

// ---------------- init C[M,N] rows with bias0(+bias1) -----------------------
__global__ __launch_bounds__(256) void init_bias2(
    float* __restrict__ C, const float* __restrict__ b0,
    const float* __restrict__ b1, int total, int N) {
  int i = blockIdx.x * 256 + threadIdx.x;
  if (i >= total) return;
  int n = i % N;
  float v = b0[n];
  if (b1) v += b1[n];
  C[i] = v;
}

// ---------------- LSTM1 recurrence: 64 blocks (per batch), 128 threads ------
__global__ __launch_bounds__(128) void lstm1_scan(
    const float* __restrict__ X1, const float* __restrict__ Whh,
    float* __restrict__ y1) {
  __shared__ float sW[128 * 33];
  __shared__ float sh[32];
  __shared__ float sg[128];
  int b = blockIdx.x, g = threadIdx.x;
  for (int i = g; i < 128 * 32; i += 128) { int r = i >> 5, c = i & 31; sW[r * 33 + c] = Whh[i]; }
  if (g < 32) sh[g] = 0.f;
  float cst = 0.f;
  __syncthreads();
  for (int t = 0; t < TSTEPS; t++) {
    float acc = X1[(size_t)(t * 64 + b) * 128 + g];
#pragma unroll
    for (int k = 0; k < 32; k++) acc += sh[k] * sW[g * 33 + k];
    sg[g] = acc;
    __syncthreads();
    if (g < 32) {
      float iv = sg[g], fv = sg[32 + g], gv = sg[64 + g], ov = sg[96 + g];
      float si = 1.f / (1.f + expf(-iv));
      float sf = 1.f / (1.f + expf(-fv));
      float so = 1.f / (1.f + expf(-ov));
      cst = sf * cst + si * tanhf(gv);
      float hn = so * tanhf(cst);
      sh[g] = hn;
      y1[(size_t)(t * 64 + b) * 32 + g] = hn;
    }
    __syncthreads();
  }
}

// ---------------- LSTM2 recurrence: 64 blocks (per batch), 512 threads ------
__global__ __launch_bounds__(512) void lstm2_scan(
    const float* __restrict__ X2, const float* __restrict__ Whh,
    float* __restrict__ h2) {
  __shared__ float sh[128];
  __shared__ float sg[512];
  int b = blockIdx.x, g = threadIdx.x;
  if (g < 128) sh[g] = 0.f;
  float cst = 0.f;
  __syncthreads();
  const float4* wp = (const float4*)(Whh + (size_t)g * 128);
  for (int t = 0; t < TSTEPS; t++) {
    float acc = X2[(size_t)(t * 64 + b) * 512 + g];
#pragma unroll 8
    for (int q = 0; q < 32; q++) {
      float4 w = wp[q];
      acc += sh[q * 4 + 0] * w.x + sh[q * 4 + 1] * w.y +
             sh[q * 4 + 2] * w.z + sh[q * 4 + 3] * w.w;
    }
    sg[g] = acc;
    __syncthreads();
    if (g < 128) {
      float iv = sg[g], fv = sg[128 + g], gv = sg[256 + g], ov = sg[384 + g];
      float si = 1.f / (1.f + expf(-iv));
      float sf = 1.f / (1.f + expf(-fv));
      float so = 1.f / (1.f + expf(-ov));
      cst = sf * cst + si * tanhf(gv);
      float hn = so * tanhf(cst);
      sh[g] = hn;
      if (t == TSTEPS - 1) h2[(size_t)b * 128 + g] = hn;
    }
    __syncthreads();
  }
}

extern "C" void kernel_launch(void* const* d_in, const int* in_sizes, int n_in,
                              void* d_out, int out_size, void* d_ws, size_t ws_size,
                              hipStream_t stream) {
  const float* x        = (const float*)d_in[0];
  const int*   ei       = (const int*)d_in[1];
  const float* gat_W    = (const float*)d_in[2];
  const float* att_src  = (const float*)d_in[3];
  const float* att_dst  = (const float*)d_in[4];
  const float* gat_bias = (const float*)d_in[5];
  const float* l1_Wih   = (const float*)d_in[6];
  const float* l1_Whh   = (const float*)d_in[7];
  const float* l1_bih   = (const float*)d_in[8];
  const float* l1_bhh   = (const float*)d_in[9];
  const float* l2_Wih   = (const float*)d_in[10];
  const float* l2_Whh   = (const float*)d_in[11];
  const float* l2_bih   = (const float*)d_in[12];
  const float* l2_bhh   = (const float*)d_in[13];
  const float* lin1_W   = (const float*)d_in[14];
  const float* lin1_b   = (const float*)d_in[15];
  const float* lin2_W   = (const float*)d_in[16];
  const float* lin2_b   = (const float*)d_in[17];
  float* out = (float*)d_out;

  float* ws    = (float*)d_ws;
  float* a_src = ws;                       // 524288
  float* a_dst = a_src + 524288;           // 524288
  float* uv    = a_dst + 524288;           // 256
  float* gT    = uv + 256;                 // 786432
  float* X1    = gT + 786432;              // 98304
  float* y1    = X1 + 98304;               // 24576
  float* X2    = y1 + 24576;               // 393216
  float* h2    = X2 + 393216;              // 8192
  float* o1    = h2 + 8192;                // 393216
  int* counts  = (int*)(o1 + 393216);      // 65536
  int* offsets = counts + 65536;           // 65536
  int* cursor  = offsets + 65536;          // 65536
  int* csr     = cursor + 65536;           // 1114112

  hipMemsetAsync(counts, 0, 65536 * sizeof(int), stream);

  gat_prep<<<1, 128, 0, stream>>>(gat_W, att_src, att_dst, uv);
  gat_node2<<<NNODES / 256, 256, 0, stream>>>(x, uv, a_src, a_dst);
  csr_count<<<(NITEMS + 255) / 256, 256, 0, stream>>>(ei, counts);
  csr_scan<<<1, 1024, 0, stream>>>(counts, offsets, cursor);
  csr_scatter<<<(NITEMS + 255) / 256, 256, 0, stream>>>(ei, cursor, csr);
  gat_agg<<<NNODES / 4, 256, 0, stream>>>(offsets, counts, csr, a_src,
                                          a_dst, x, gat_W, gat_bias, gT);

  // X1 = gT[768,1024] @ l1_Wih[128,1024]^T + bih + bhh  (split-K=8, atomic)
  init_bias2<<<(768 * 128 + 255) / 256, 256, 0, stream>>>(X1, l1_bih, l1_bhh, 768 * 128, 128);
  {
    dim3 g(128 / 64, 768 / 64, 8);
    gemm_bt<true><<<g, 256, 0, stream>>>(gT, l1_Wih, nullptr, nullptr, X1, 768, 128, 1024, 1024 / 8);
  }
  lstm1_scan<<<64, 128, 0, stream>>>(X1, l1_Whh, y1);

  // X2 = y1[768,32] @ l2_Wih[512,32]^T + bih + bhh
  {
    dim3 g(512 / 64, 768 / 64, 1);
    gemm_bt<false><<<g, 256, 0, stream>>>(y1, l2_Wih, l2_bih, l2_bhh, X2, 768, 512, 32, 32);
  }
  lstm2_scan<<<64, 512, 0, stream>>>(X2, l2_Whh, h2);

  // o1 = h2[64,128] @ lin1_W[6144,128]^T + lin1_b
  {
    dim3 g(6144 / 64, 64 / 64, 1);
    gemm_bt<false><<<g, 256, 0, stream>>>(h2, lin1_W, lin1_b, nullptr, o1, 64, 6144, 128, 128);
  }

  // out = o1[64,6144] @ lin2_W[12288,6144]^T + lin2_b  (split-K=16, atomic)
  init_bias2<<<(NBATCH * 12288 + 255) / 256, 256, 0, stream>>>(out, lin2_b, nullptr, NBATCH * 12288, 12288);
  {
    dim3 g(12288 / 64, 64 / 64, 16);
    gemm_bt<true><<<g, 256, 0, stream>>>(o1, lin2_W, nullptr, nullptr, out, 64, 12288, 6144, 6144 / 16);
  }
}

// Round 10
// 897.127 us; speedup vs baseline: 1.0677x; 1.0677x over previous
//
#include <hip/hip_runtime.h>
#include <math.h>

#define NNODES 65536
#define CH 12
#define NHEADS 8
#define NEDGE 1048576
#define NITEMS (NEDGE + NNODES)
#define NBATCH 64
#define TSTEPS 12

// ---- prep: u[h][k] = sum_c att_src[h][c]*W[(h*12+c)][k], v likewise --------
__global__ __launch_bounds__(128) void gat_prep(
    const float* __restrict__ W, const float* __restrict__ as,
    const float* __restrict__ ad, float* __restrict__ uv) {
  int t = threadIdx.x;
  if (t < 96) {
    int h = t / 12, k = t % 12;
    float su = 0.f, sv = 0.f;
#pragma unroll
    for (int c = 0; c < 12; c++) {
      float w = W[(h * 12 + c) * 12 + k];
      su += as[h * 12 + c] * w;
      sv += ad[h * 12 + c] * w;
    }
    uv[t] = su; uv[96 + t] = sv;
  }
}

// ---- per-node attention scalars: a_src[n][h]=u_h.x_n, a_dst[n][h]=v_h.x_n --
__global__ __launch_bounds__(256) void gat_node2(
    const float* __restrict__ x, const float* __restrict__ uv,
    float* __restrict__ a_src, float* __restrict__ a_dst) {
  __shared__ float su[96], sv[96];
  int tid = threadIdx.x;
  if (tid < 96) { su[tid] = uv[tid]; sv[tid] = uv[96 + tid]; }
  __syncthreads();
  int n = blockIdx.x * 256 + tid;
  const float4* xp = (const float4*)(x + (size_t)n * 12);
  float4 x0 = xp[0], x1 = xp[1], x2 = xp[2];
  float xv[12] = {x0.x,x0.y,x0.z,x0.w,x1.x,x1.y,x1.z,x1.w,x2.x,x2.y,x2.z,x2.w};
  float as[8], ad[8];
#pragma unroll
  for (int h = 0; h < 8; h++) {
    float s1 = 0.f, s2 = 0.f;
#pragma unroll
    for (int k = 0; k < 12; k++) { s1 += su[h*12+k]*xv[k]; s2 += sv[h*12+k]*xv[k]; }
    as[h] = s1; ad[h] = s2;
  }
  float4* ap = (float4*)(a_src + (size_t)n * 8);
  float4* dp = (float4*)(a_dst + (size_t)n * 8);
  ap[0] = make_float4(as[0],as[1],as[2],as[3]);
  ap[1] = make_float4(as[4],as[5],as[6],as[7]);
  dp[0] = make_float4(ad[0],ad[1],ad[2],ad[3]);
  dp[1] = make_float4(ad[4],ad[5],ad[6],ad[7]);
}

// ---- CSR build: count / scan / scatter -------------------------------------
__global__ __launch_bounds__(256) void csr_count(const int* __restrict__ ei,
                                                 int* __restrict__ counts) {
  int e = blockIdx.x * 256 + threadIdx.x;
  if (e >= NITEMS) return;
  int d = (e < NEDGE) ? ei[NEDGE + e] : (e - NEDGE);
  atomicAdd(&counts[d], 1);
}

__global__ __launch_bounds__(1024) void csr_scan(const int* __restrict__ counts,
                                                 int* __restrict__ offsets,
                                                 int* __restrict__ cursor) {
  __shared__ int part[1024];
  int t = threadIdx.x;
  int base = t * 64;
  int s = 0;
  for (int i = 0; i < 64; i++) s += counts[base + i];
  part[t] = s;
  __syncthreads();
  for (int off = 1; off < 1024; off <<= 1) {
    int v = (t >= off) ? part[t - off] : 0;
    __syncthreads();
    part[t] += v;
    __syncthreads();
  }
  int run = (t == 0) ? 0 : part[t - 1];
  for (int i = 0; i < 64; i++) {
    offsets[base + i] = run;
    cursor[base + i] = run;
    run += counts[base + i];
  }
}

__global__ __launch_bounds__(256) void csr_scatter(const int* __restrict__ ei,
                                                   int* __restrict__ cursor,
                                                   int* __restrict__ csr) {
  int e = blockIdx.x * 256 + threadIdx.x;
  if (e >= NITEMS) return;
  int s, d;
  if (e < NEDGE) { s = ei[e]; d = ei[NEDGE + e]; } else { s = d = e - NEDGE; }
  int pos = atomicAdd(&cursor[d], 1);
  csr[pos] = s;
}

// ---- fused GAT aggregation: one WAVE per dst node --------------------------
__global__ __launch_bounds__(256) void gat_agg(
    const int* __restrict__ offsets, const int* __restrict__ counts,
    const int* __restrict__ csr, const float* __restrict__ a_src,
    const float* __restrict__ a_dst, const float* __restrict__ x,
    const float* __restrict__ gat_W, const float* __restrict__ gat_bias,
    float* __restrict__ gT) {
  __shared__ float sW[1152];
  __shared__ float sB[12];
  int tid = threadIdx.x;
  for (int i = tid; i < 1152; i += 256) sW[i] = gat_W[i];
  if (tid < 12) sB[tid] = gat_bias[tid];
  __syncthreads();
  int wave = tid >> 6, lane = tid & 63;
  int d = blockIdx.x * 4 + wave;
  int h = lane & 7, sub = lane >> 3;
  int start = offsets[d], deg = counts[d];
  float adh = a_dst[(size_t)d * 8 + h];
  float denom = 0.f;
  for (int i = sub; i < deg; i += 8) {
    int s = csr[start + i];
    float e = a_src[(size_t)s * 8 + h] + adh;
    e = e > 0.f ? e : 0.2f * e;
    denom += expf(e);
  }
  denom += __shfl_xor(denom, 8);
  denom += __shfl_xor(denom, 16);
  denom += __shfl_xor(denom, 32);
  float inv = 1.f / (denom + 1e-16f);
  float acc[12];
#pragma unroll
  for (int c = 0; c < 12; c++) acc[c] = 0.f;
  for (int i = sub; i < deg; i += 8) {
    int s = csr[start + i];
    float e = a_src[(size_t)s * 8 + h] + adh;
    e = e > 0.f ? e : 0.2f * e;
    float al = expf(e) * inv;
    const float4* xp = (const float4*)(x + (size_t)s * 12);
    float4 x0 = xp[0], x1 = xp[1], x2 = xp[2];
    acc[0] += al*x0.x; acc[1] += al*x0.y; acc[2]  += al*x0.z; acc[3]  += al*x0.w;
    acc[4] += al*x1.x; acc[5] += al*x1.y; acc[6]  += al*x1.z; acc[7]  += al*x1.w;
    acc[8] += al*x2.x; acc[9] += al*x2.y; acc[10] += al*x2.z; acc[11] += al*x2.w;
  }
  float y[12];
#pragma unroll
  for (int c = 0; c < 12; c++) {
    const float* wr = sW + (h * 12 + c) * 12;
    float t = 0.f;
#pragma unroll
    for (int k = 0; k < 12; k++) t += wr[k] * acc[k];
    y[c] = t;
  }
#pragma unroll
  for (int off = 1; off < 64; off <<= 1) {
#pragma unroll
    for (int c = 0; c < 12; c++) y[c] += __shfl_xor(y[c], off);
  }
  if (lane == 0) {
    int b = d >> 10, np = d & 1023;
#pragma unroll
    for (int t = 0; t < 12; t++)
      gT[((size_t)(t * 64 + b)) * 1024 + np] = y[t] * 0.125f + sB[t];
  }
}

// ---------------- generic tiled GEMM: C[M,N] = A[M,K] @ B[N,K]^T (+bias) ----
template <bool ATOMIC>
__global__ __launch_bounds__(256) void gemm_bt(
    const float* __restrict__ A, const float* __restrict__ B,
    const float* __restrict__ bias0, const float* __restrict__ bias1,
    float* __restrict__ C, int M, int N, int K, int kLen) {
  __shared__ float As[16][68];
  __shared__ float Bs[16][68];
  int m0 = blockIdx.y * 64, n0 = blockIdx.x * 64;
  int k0 = blockIdx.z * kLen;
  int tid = threadIdx.x;
  int lr = tid >> 2, lq = tid & 3;
  int tn = tid & 15, tm = tid >> 4;
  float acc[4][4];
#pragma unroll
  for (int i = 0; i < 4; i++)
#pragma unroll
    for (int j = 0; j < 4; j++) acc[i][j] = 0.f;

  const float* Ap = A + (size_t)(m0 + lr) * K + k0 + lq * 4;
  const float* Bp = B + (size_t)(n0 + lr) * K + k0 + lq * 4;
  float4 a4 = *(const float4*)Ap;
  float4 b4 = *(const float4*)Bp;

  for (int kk = 0; kk < kLen; kk += 16) {
    As[lq * 4 + 0][lr] = a4.x; As[lq * 4 + 1][lr] = a4.y;
    As[lq * 4 + 2][lr] = a4.z; As[lq * 4 + 3][lr] = a4.w;
    Bs[lq * 4 + 0][lr] = b4.x; Bs[lq * 4 + 1][lr] = b4.y;
    Bs[lq * 4 + 2][lr] = b4.z; Bs[lq * 4 + 3][lr] = b4.w;
    __syncthreads();
    float4 a4n, b4n;
    if (kk + 16 < kLen) {
      a4n = *(const float4*)(Ap + kk + 16);
      b4n = *(const float4*)(Bp + kk + 16);
    }
#pragma unroll
    for (int k = 0; k < 16; k++) {
      float4 av = *(const float4*)(&As[k][tm * 4]);
      float4 bv = *(const float4*)(&Bs[k][tn * 4]);
      acc[0][0] += av.x * bv.x; acc[0][1] += av.x * bv.y; acc[0][2] += av.x * bv.z; acc[0][3] += av.x * bv.w;
      acc[1][0] += av.y * bv.x; acc[1][1] += av.y * bv.y; acc[1][2] += av.y * bv.z; acc[1][3] += av.y * bv.w;
      acc[2][0] += av.z * bv.x; acc[2][1] += av.z * bv.y; acc[2][2] += av.z * bv.z; acc[2][3] += av.z * bv.w;
      acc[3][0] += av.w * bv.x; acc[3][1] += av.w * bv.y; acc[3][2] += av.w * bv.z; acc[3][3] += av.w * bv.w;
    }
    __syncthreads();
    a4 = a4n; b4 = b4n;
  }
#pragma unroll
  for (int i = 0; i < 4; i++) {
    int m = m0 + tm * 4 + i;
#pragma unroll
    for (int j = 0; j < 4; j++) {
      int n = n0 + tn * 4 + j;
      float v = acc[i][j];
      if (ATOMIC) {
        atomicAdd(&C[(size_t)m * N + n], v);
      } else {
        v += bias0[n];
        if (bias1) v += bias1[n];
        C[(size_t)m * N + n] = v;
      }
    }
  }
}

// ---- split-K GEMM into PARTIAL buffers (no atomics), double-buffered LDS ---
// Cp layout: [z][M][N]; grid (N/64, M/64, SPLITZ); kLen = K/SPLITZ (mult of 16)
__global__ __launch_bounds__(256) void gemm_bt_part(
    const float* __restrict__ A, const float* __restrict__ B,
    float* __restrict__ Cp, int M, int N, int K, int kLen) {
  __shared__ float As[2][16][68];
  __shared__ float Bs[2][16][68];
  int m0 = blockIdx.y * 64, n0 = blockIdx.x * 64;
  int z = blockIdx.z;
  int k0 = z * kLen;
  int tid = threadIdx.x;
  int lr = tid >> 2, lq = tid & 3;
  int tn = tid & 15, tm = tid >> 4;
  float acc[4][4];
#pragma unroll
  for (int i = 0; i < 4; i++)
#pragma unroll
    for (int j = 0; j < 4; j++) acc[i][j] = 0.f;

  const float* Ap = A + (size_t)(m0 + lr) * K + k0 + lq * 4;
  const float* Bp = B + (size_t)(n0 + lr) * K + k0 + lq * 4;
  {
    float4 a4 = *(const float4*)Ap;
    float4 b4 = *(const float4*)Bp;
    As[0][lq * 4 + 0][lr] = a4.x; As[0][lq * 4 + 1][lr] = a4.y;
    As[0][lq * 4 + 2][lr] = a4.z; As[0][lq * 4 + 3][lr] = a4.w;
    Bs[0][lq * 4 + 0][lr] = b4.x; Bs[0][lq * 4 + 1][lr] = b4.y;
    Bs[0][lq * 4 + 2][lr] = b4.z; Bs[0][lq * 4 + 3][lr] = b4.w;
  }
  __syncthreads();
  int buf = 0;
  for (int kk = 16; kk < kLen; kk += 16) {
    float4 a4n = *(const float4*)(Ap + kk);
    float4 b4n = *(const float4*)(Bp + kk);
#pragma unroll
    for (int k = 0; k < 16; k++) {
      float4 av = *(const float4*)(&As[buf][k][tm * 4]);
      float4 bv = *(const float4*)(&Bs[buf][k][tn * 4]);
      acc[0][0] += av.x * bv.x; acc[0][1] += av.x * bv.y; acc[0][2] += av.x * bv.z; acc[0][3] += av.x * bv.w;
      acc[1][0] += av.y * bv.x; acc[1][1] += av.y * bv.y; acc[1][2] += av.y * bv.z; acc[1][3] += av.y * bv.w;
      acc[2][0] += av.z * bv.x; acc[2][1] += av.z * bv.y; acc[2][2] += av.z * bv.z; acc[2][3] += av.z * bv.w;
      acc[3][0] += av.w * bv.x; acc[3][1] += av.w * bv.y; acc[3][2] += av.w * bv.z; acc[3][3] += av.w * bv.w;
    }
    int nb = buf ^ 1;
    As[nb][lq * 4 + 0][lr] = a4n.x; As[nb][lq * 4 + 1][lr] = a4n.y;
    As[nb][lq * 4 + 2][lr] = a4n.z; As[nb][lq * 4 + 3][lr] = a4n.w;
    Bs[nb][lq * 4 + 0][lr] = b4n.x; Bs[nb][lq * 4 + 1][lr] = b4n.y;
    Bs[nb][lq * 4 + 2][lr] = b4n.z; Bs[nb][lq * 4 + 3][lr] = b4n.w;
    __syncthreads();
    buf = nb;
  }
#pragma unroll
  for (int k = 0; k < 16; k++) {
    float4 av = *(const float4*)(&As[buf][k][tm * 4]);
    float4 bv = *(const float4*)(&Bs[buf][k][tn * 4]);
    acc[0][0] += av.x * bv.x; acc[0][1] += av.x * bv.y; acc[0][2] += av.x * bv.z; acc[0][3] += av.x * bv.w;
    acc[1][0] += av.y * bv.x; acc[1][1] += av.y * bv.y; acc[1][2] += av.y * bv.z; acc[1][3] += av.y * bv.w;
    acc[2][0] += av.z * bv.x; acc[2][1] += av.z * bv.y; acc[2][2] += av.z * bv.z; acc[2][3] += av.z * bv.w;
    acc[3][0] += av.w * bv.x; acc[3][1] += av.w * bv.y; acc[3][2] += av.w * bv.z; acc[3][3] += av.w * bv.w;
  }
  float* Cz = Cp + (size_t)z * M * N;
#pragma unroll
  for (int i = 0; i < 4; i++) {
    int m = m0 + tm * 4 + i;
#pragma unroll
    for (int j = 0; j < 4; j++) {
      Cz[(size_t)m * N + n0 + tn * 4 + j] = acc[i][j];
    }
  }
}

// ---- sum 8 partial buffers + bias -> out -----------------------------------
__global__ __launch_bounds__(256) void reduce_parts(
    const float* __restrict__ Cp, const float* __restrict__ bias,
    float* __restrict__ out, int MN, int N) {
  int i = blockIdx.x * 256 + threadIdx.x;   // float4 index
  if (i * 4 >= MN) return;
  float4 s = ((const float4*)Cp)[i];
#pragma unroll
  for (int z = 1; z < 8; z++) {
    float4 v = ((const float4*)(Cp + (size_t)z * MN))[i];
    s.x += v.x; s.y += v.y; s.z += v.z; s.w += v.w;
  }
  int n = (i * 4) % N;
  float4 b = *(const float4*)(bias + n);
  s.x += b.x; s.y += b.y; s.z += b.z; s.w += b.w;
  ((float4*)out)[i] = s;
}

// ---------------- init C[M,N] rows with bias0(+bias1) -----------------------
__global__ __launch_bounds__(256) void init_bias2(
    float* __restrict__ C, const float* __restrict__ b0,
    const float* __restrict__ b1, int total, int N) {
  int i = blockIdx.x * 256 + threadIdx.x;
  if (i >= total) return;
  int n = i % N;
  float v = b0[n];
  if (b1) v += b1[n];
  C[i] = v;
}

// ---------------- LSTM1 recurrence: 64 blocks (per batch), 128 threads ------
__global__ __launch_bounds__(128) void lstm1_scan(
    const float* __restrict__ X1, const float* __restrict__ Whh,
    float* __restrict__ y1) {
  __shared__ float sW[128 * 33];
  __shared__ float sh[32];
  __shared__ float sg[128];
  int b = blockIdx.x, g = threadIdx.x;
  for (int i = g; i < 128 * 32; i += 128) { int r = i >> 5, c = i & 31; sW[r * 33 + c] = Whh[i]; }
  if (g < 32) sh[g] = 0.f;
  float cst = 0.f;
  __syncthreads();
  for (int t = 0; t < TSTEPS; t++) {
    float acc = X1[(size_t)(t * 64 + b) * 128 + g];
#pragma unroll
    for (int k = 0; k < 32; k++) acc += sh[k] * sW[g * 33 + k];
    sg[g] = acc;
    __syncthreads();
    if (g < 32) {
      float iv = sg[g], fv = sg[32 + g], gv = sg[64 + g], ov = sg[96 + g];
      float si = 1.f / (1.f + expf(-iv));
      float sf = 1.f / (1.f + expf(-fv));
      float so = 1.f / (1.f + expf(-ov));
      cst = sf * cst + si * tanhf(gv);
      float hn = so * tanhf(cst);
      sh[g] = hn;
      y1[(size_t)(t * 64 + b) * 32 + g] = hn;
    }
    __syncthreads();
  }
}

// ---------------- LSTM2 recurrence: 64 blocks (per batch), 512 threads ------
__global__ __launch_bounds__(512) void lstm2_scan(
    const float* __restrict__ X2, const float* __restrict__ Whh,
    float* __restrict__ h2) {
  __shared__ float sh[128];
  __shared__ float sg[512];
  int b = blockIdx.x, g = threadIdx.x;
  if (g < 128) sh[g] = 0.f;
  float cst = 0.f;
  __syncthreads();
  const float4* wp = (const float4*)(Whh + (size_t)g * 128);
  for (int t = 0; t < TSTEPS; t++) {
    float acc = X2[(size_t)(t * 64 + b) * 512 + g];
#pragma unroll 8
    for (int q = 0; q < 32; q++) {
      float4 w = wp[q];
      acc += sh[q * 4 + 0] * w.x + sh[q * 4 + 1] * w.y +
             sh[q * 4 + 2] * w.z + sh[q * 4 + 3] * w.w;
    }
    sg[g] = acc;
    __syncthreads();
    if (g < 128) {
      float iv = sg[g], fv = sg[128 + g], gv = sg[256 + g], ov = sg[384 + g];
      float si = 1.f / (1.f + expf(-iv));
      float sf = 1.f / (1.f + expf(-fv));
      float so = 1.f / (1.f + expf(-ov));
      cst = sf * cst + si * tanhf(gv);
      float hn = so * tanhf(cst);
      sh[g] = hn;
      if (t == TSTEPS - 1) h2[(size_t)b * 128 + g] = hn;
    }
    __syncthreads();
  }
}

extern "C" void kernel_launch(void* const* d_in, const int* in_sizes, int n_in,
                              void* d_out, int out_size, void* d_ws, size_t ws_size,
                              hipStream_t stream) {
  const float* x        = (const float*)d_in[0];
  const int*   ei       = (const int*)d_in[1];
  const float* gat_W    = (const float*)d_in[2];
  const float* att_src  = (const float*)d_in[3];
  const float* att_dst  = (const float*)d_in[4];
  const float* gat_bias = (const float*)d_in[5];
  const float* l1_Wih   = (const float*)d_in[6];
  const float* l1_Whh   = (const float*)d_in[7];
  const float* l1_bih   = (const float*)d_in[8];
  const float* l1_bhh   = (const float*)d_in[9];
  const float* l2_Wih   = (const float*)d_in[10];
  const float* l2_Whh   = (const float*)d_in[11];
  const float* l2_bih   = (const float*)d_in[12];
  const float* l2_bhh   = (const float*)d_in[13];
  const float* lin1_W   = (const float*)d_in[14];
  const float* lin1_b   = (const float*)d_in[15];
  const float* lin2_W   = (const float*)d_in[16];
  const float* lin2_b   = (const float*)d_in[17];
  float* out = (float*)d_out;

  float* ws    = (float*)d_ws;
  float* a_src = ws;                       // 524288
  float* a_dst = a_src + 524288;           // 524288
  float* uv    = a_dst + 524288;           // 256
  float* gT    = uv + 256;                 // 786432
  float* X1    = gT + 786432;              // 98304
  float* y1    = X1 + 98304;               // 24576
  float* X2    = y1 + 24576;               // 393216
  float* h2    = X2 + 393216;              // 8192
  float* o1    = h2 + 8192;                // 393216
  int* counts  = (int*)(o1 + 393216);      // 65536
  int* offsets = counts + 65536;           // 65536
  int* cursor  = offsets + 65536;          // 65536
  int* csr     = cursor + 65536;           // 1114112
  float* part  = (float*)(csr + 1114112);  // 8 * 64*12288 = 6291456

  hipMemsetAsync(counts, 0, 65536 * sizeof(int), stream);

  gat_prep<<<1, 128, 0, stream>>>(gat_W, att_src, att_dst, uv);
  gat_node2<<<NNODES / 256, 256, 0, stream>>>(x, uv, a_src, a_dst);
  csr_count<<<(NITEMS + 255) / 256, 256, 0, stream>>>(ei, counts);
  csr_scan<<<1, 1024, 0, stream>>>(counts, offsets, cursor);
  csr_scatter<<<(NITEMS + 255) / 256, 256, 0, stream>>>(ei, cursor, csr);
  gat_agg<<<NNODES / 4, 256, 0, stream>>>(offsets, counts, csr, a_src,
                                          a_dst, x, gat_W, gat_bias, gT);

  // X1 = gT[768,1024] @ l1_Wih[128,1024]^T + bih + bhh  (split-K=8, atomic)
  init_bias2<<<(768 * 128 + 255) / 256, 256, 0, stream>>>(X1, l1_bih, l1_bhh, 768 * 128, 128);
  {
    dim3 g(128 / 64, 768 / 64, 8);
    gemm_bt<true><<<g, 256, 0, stream>>>(gT, l1_Wih, nullptr, nullptr, X1, 768, 128, 1024, 1024 / 8);
  }
  lstm1_scan<<<64, 128, 0, stream>>>(X1, l1_Whh, y1);

  // X2 = y1[768,32] @ l2_Wih[512,32]^T + bih + bhh
  {
    dim3 g(512 / 64, 768 / 64, 1);
    gemm_bt<false><<<g, 256, 0, stream>>>(y1, l2_Wih, l2_bih, l2_bhh, X2, 768, 512, 32, 32);
  }
  lstm2_scan<<<64, 512, 0, stream>>>(X2, l2_Whh, h2);

  // o1 = h2[64,128] @ lin1_W[6144,128]^T + lin1_b
  {
    dim3 g(6144 / 64, 64 / 64, 1);
    gemm_bt<false><<<g, 256, 0, stream>>>(h2, lin1_W, lin1_b, nullptr, o1, 64, 6144, 128, 128);
  }

  // out = o1[64,6144] @ lin2_W[12288,6144]^T + lin2_b
  // split-K=8 into partial buffers (no atomics) + reduce
  {
    dim3 g(12288 / 64, 64 / 64, 8);
    gemm_bt_part<<<g, 256, 0, stream>>>(o1, lin2_W, part, 64, 12288, 6144, 6144 / 8);
  }
  reduce_parts<<<(64 * 12288 / 4 + 255) / 256, 256, 0, stream>>>(
      part, lin2_b, out, 64 * 12288, 12288);
}